// Round 1
// baseline (2725.981 us; speedup 1.0000x reference)
//
#include <hip/hip_runtime.h>
#include <hip/hip_bf16.h>

#define NN 50000
#define NE 1600000
#define D  128

typedef __attribute__((ext_vector_type(8))) short short8;
typedef __attribute__((ext_vector_type(4))) float f32x4;

__device__ __forceinline__ unsigned short f2b(float x) {
  unsigned u = __float_as_uint(x);
  u += 0x7fffu + ((u >> 16) & 1u);
  return (unsigned short)(u >> 16);
}
__device__ __forceinline__ float b2f(unsigned short v) {
  return __uint_as_float(((unsigned)v) << 16);
}

// Decide whether edge_index arrived as int64 (odd int32 words = high words = 0)
// or int32 (odd words are random values in [0, 50000)). Deterministic.
__global__ void detect_k(const int* __restrict__ ei, int* __restrict__ flag) {
  __shared__ int nz;
  if (threadIdx.x == 0) nz = 0;
  __syncthreads();
  int idx = 1 + 2 * ((int)threadIdx.x * (NE / 256));  // odd index < 2*NE
  if (ei[idx] != 0) atomicOr(&nz, 1);
  __syncthreads();
  if (threadIdx.x == 0) *flag = (nz == 0) ? 1 : 0;   // 1 => int64
}

// Zero the fp32 accumulator S and build the bf16 copy of h.
__global__ __launch_bounds__(256) void prep_k(const float* __restrict__ h,
                                              float* __restrict__ S,
                                              unsigned short* __restrict__ hb) {
  int i = blockIdx.x * 256 + threadIdx.x;  // one float4-group
  float4 x = ((const float4*)h)[i];
  ushort4 o;
  o.x = f2b(x.x); o.y = f2b(x.y); o.z = f2b(x.z); o.w = f2b(x.w);
  ((ushort4*)hb)[i] = o;
  ((float4*)S)[i] = make_float4(0.f, 0.f, 0.f, 0.f);
}

// W1 = W_upd[:, :128] -> bf16 ; Wc = W_upd[:, 128:] @ W_msg -> bf16
__global__ __launch_bounds__(256) void wprep_k(const float* __restrict__ Wm,
                                               const float* __restrict__ Wu,
                                               unsigned short* __restrict__ W1b,
                                               unsigned short* __restrict__ Wcb) {
  int tid = blockIdx.x * 256 + threadIdx.x;  // 0..16383
  int o = tid >> 7, j = tid & 127;
  W1b[tid] = f2b(Wu[o * 256 + j]);
  float acc = 0.f;
#pragma unroll 4
  for (int k = 0; k < 128; ++k)
    acc += Wu[o * 256 + 128 + k] * Wm[k * 128 + j];
  Wcb[tid] = f2b(acc);
}

// 32 lanes per edge: gather bf16 h[src] row (256B coalesced), fp32 atomics into S[dst].
__global__ __launch_bounds__(256) void scatter_k(const int* __restrict__ ei,
                                                 const int* __restrict__ flag,
                                                 const unsigned short* __restrict__ hb,
                                                 float* __restrict__ S) {
  const unsigned tid = blockIdx.x * 256u + threadIdx.x;
  const unsigned e = tid >> 5;
  const unsigned l = tid & 31u;
  int src, dst;
  if (*flag) {  // int64 storage: read low words
    src = ei[2u * e];
    dst = ei[2u * (NE + e)];
  } else {      // int32 storage
    src = ei[e];
    dst = ei[NE + e];
  }
  ushort4 v = *(const ushort4*)(hb + (size_t)src * D + l * 4u);
  float* sp = S + (size_t)dst * D + l * 4u;
  atomicAdd(sp + 0, b2f(v.x));
  atomicAdd(sp + 1, b2f(v.y));
  atomicAdd(sp + 2, b2f(v.z));
  atomicAdd(sp + 3, b2f(v.w));
}

// out = relu([h | S] @ [W1 | Wc]^T + b), bf16 MFMA 16x16x32, K=256, N=128.
// Weights (2 x 32KB bf16) are L1/L2 resident; no LDS needed.
__global__ __launch_bounds__(256) void gemm_k(const unsigned short* __restrict__ hb,
                                              const float* __restrict__ S,
                                              const unsigned short* __restrict__ W1b,
                                              const unsigned short* __restrict__ Wcb,
                                              const float* __restrict__ bias,
                                              float* __restrict__ out) {
  const int wave = threadIdx.x >> 6;
  const int lane = threadIdx.x & 63;
  const int r = lane & 15;   // A-row / B-col / C-col within 16
  const int g = lane >> 4;   // k-group; C-row group
  const int row0 = blockIdx.x * 64 + wave * 16;
  const int row = min(row0 + r, NN - 1);  // clamp; stores are guarded

  f32x4 acc[8];
#pragma unroll
  for (int t = 0; t < 8; ++t) acc[t] = (f32x4){0.f, 0.f, 0.f, 0.f};

#pragma unroll
  for (int c = 0; c < 8; ++c) {
    const int k0 = (c & 3) * 32 + g * 8;
    short8 a;
    if (c < 4) {  // K 0..127 from h (bf16)
      a = *(const short8*)(hb + (size_t)row * D + k0);
    } else {      // K 128..255 from S (fp32 -> bf16 inline)
      const float* sp = S + (size_t)row * D + k0;
      float4 s0 = ((const float4*)sp)[0];
      float4 s1 = ((const float4*)sp)[1];
      a[0] = (short)f2b(s0.x); a[1] = (short)f2b(s0.y);
      a[2] = (short)f2b(s0.z); a[3] = (short)f2b(s0.w);
      a[4] = (short)f2b(s1.x); a[5] = (short)f2b(s1.y);
      a[6] = (short)f2b(s1.z); a[7] = (short)f2b(s1.w);
    }
    const unsigned short* W = (c < 4) ? W1b : Wcb;
#pragma unroll
    for (int t = 0; t < 8; ++t) {
      short8 b = *(const short8*)(W + (size_t)(t * 16 + r) * D + k0);
      acc[t] = __builtin_amdgcn_mfma_f32_16x16x32_bf16(a, b, acc[t], 0, 0, 0);
    }
  }

#pragma unroll
  for (int t = 0; t < 8; ++t) {
    const int col = t * 16 + r;
    const float bv = bias[col];
#pragma unroll
    for (int j = 0; j < 4; ++j) {
      const int orow = row0 + g * 4 + j;
      if (orow < NN) {
        float v = acc[t][j] + bv;
        out[(size_t)orow * D + col] = v > 0.f ? v : 0.f;
      }
    }
  }
}

extern "C" void kernel_launch(void* const* d_in, const int* in_sizes, int n_in,
                              void* d_out, int out_size, void* d_ws, size_t ws_size,
                              hipStream_t stream) {
  const float* h    = (const float*)d_in[0];
  const int*   ei   = (const int*)d_in[1];
  const float* Wm   = (const float*)d_in[2];
  const float* Wu   = (const float*)d_in[3];
  const float* bu   = (const float*)d_in[4];
  float* out = (float*)d_out;

  char* ws = (char*)d_ws;
  float*          S   = (float*)(ws);                    // 25,600,000 B
  unsigned short* hb  = (unsigned short*)(ws + 25600000); // 12,800,000 B
  unsigned short* W1b = (unsigned short*)(ws + 38400000); // 32,768 B
  unsigned short* Wcb = (unsigned short*)(ws + 38432768); // 32,768 B
  int*            flg = (int*)(ws + 38465536);            // 4 B

  detect_k<<<1, 256, 0, stream>>>(ei, flg);
  prep_k<<<(NN * D / 4) / 256, 256, 0, stream>>>(h, S, hb);        // 6250 blocks
  wprep_k<<<64, 256, 0, stream>>>(Wm, Wu, W1b, Wcb);
  scatter_k<<<(NE * 32) / 256, 256, 0, stream>>>(ei, flg, hb, S);  // 200000 blocks
  gemm_k<<<(NN + 63) / 64, 256, 0, stream>>>(hb, S, W1b, Wcb, bu, out); // 782 blocks
}

// Round 2
// 359.824 us; speedup vs baseline: 7.5759x; 7.5759x over previous
//
#include <hip/hip_runtime.h>
#include <hip/hip_bf16.h>

#define NN 50000
#define NE 1600000
#define D  128

typedef __attribute__((ext_vector_type(8))) short short8;
typedef __attribute__((ext_vector_type(4))) float f32x4;

__device__ __forceinline__ unsigned short f2b(float x) {
  unsigned u = __float_as_uint(x);
  u += 0x7fffu + ((u >> 16) & 1u);
  return (unsigned short)(u >> 16);
}
__device__ __forceinline__ float b2f(unsigned short v) {
  return __uint_as_float(((unsigned)v) << 16);
}

// Decide whether edge_index arrived as int64 (odd int32 words = high words = 0)
// or int32 (odd words are random values in [0, 50000)). Deterministic.
__global__ void detect_k(const int* __restrict__ ei, int* __restrict__ flag) {
  __shared__ int nz;
  if (threadIdx.x == 0) nz = 0;
  __syncthreads();
  int idx = 1 + 2 * ((int)threadIdx.x * (NE / 256));  // odd index < 2*NE
  if (ei[idx] != 0) atomicOr(&nz, 1);
  __syncthreads();
  if (threadIdx.x == 0) *flag = (nz == 0) ? 1 : 0;   // 1 => int64
}

// hb = bf16(h); zero the degree histogram.
__global__ __launch_bounds__(256) void prep_k(const float* __restrict__ h,
                                              unsigned short* __restrict__ hb,
                                              int* __restrict__ count) {
  int i = blockIdx.x * 256 + threadIdx.x;  // one float4-group, 1.6M threads
  float4 x = ((const float4*)h)[i];
  ushort4 o;
  o.x = f2b(x.x); o.y = f2b(x.y); o.z = f2b(x.z); o.w = f2b(x.w);
  ((ushort4*)hb)[i] = o;
  if (i < NN) count[i] = 0;
}

// W1 = W_upd[:, :128] -> bf16 ; Wc = W_upd[:, 128:] @ W_msg -> bf16
__global__ __launch_bounds__(256) void wprep_k(const float* __restrict__ Wm,
                                               const float* __restrict__ Wu,
                                               unsigned short* __restrict__ W1b,
                                               unsigned short* __restrict__ Wcb) {
  int tid = blockIdx.x * 256 + threadIdx.x;  // 0..16383
  int o = tid >> 7, j = tid & 127;
  W1b[tid] = f2b(Wu[o * 256 + j]);
  float acc = 0.f;
#pragma unroll 4
  for (int k = 0; k < 128; ++k)
    acc += Wu[o * 256 + 128 + k] * Wm[k * 128 + j];
  Wcb[tid] = f2b(acc);
}

// Degree histogram over dst. 1.6M int atomics (vs 204.8M f32 before).
__global__ __launch_bounds__(256) void hist_k(const int* __restrict__ ei,
                                              const int* __restrict__ flag,
                                              int* __restrict__ count) {
  int e = blockIdx.x * 256 + threadIdx.x;
  int dst = (*flag) ? ei[2 * (NE + (size_t)e)] : ei[NE + e];
  atomicAdd(count + dst, 1);
}

// Single-block exclusive scan of count[0..NN) -> offs, cursor; offs[NN]=NE.
__global__ __launch_bounds__(1024) void scan_k(const int* __restrict__ count,
                                               int* __restrict__ offs,
                                               int* __restrict__ cursor) {
  __shared__ int wsum[16];
  __shared__ int srun_s;
  const int tid = threadIdx.x, lane = tid & 63, wv = tid >> 6;
  if (tid == 0) srun_s = 0;
  __syncthreads();
  for (int base = 0; base < NN; base += 1024) {
    int i = base + tid;
    int v = (i < NN) ? count[i] : 0;
    int s = v;  // inclusive wave scan
#pragma unroll
    for (int d = 1; d < 64; d <<= 1) {
      int t = __shfl_up(s, d, 64);
      if (lane >= d) s += t;
    }
    if (lane == 63) wsum[wv] = s;
    __syncthreads();
    if (wv == 0) {
      int ws = (lane < 16) ? wsum[lane] : 0;
#pragma unroll
      for (int d = 1; d < 16; d <<= 1) {
        int t = __shfl_up(ws, d, 64);
        if (lane >= d) ws += t;
      }
      if (lane < 16) wsum[lane] = ws;  // inclusive wave-sums scan
    }
    __syncthreads();
    int excl = srun_s + (wv ? wsum[wv - 1] : 0) + (s - v);
    if (i < NN) { offs[i] = excl; cursor[i] = excl; }
    __syncthreads();
    if (tid == 0) srun_s += wsum[15];
    __syncthreads();
  }
  if (tid == 0) offs[NN] = srun_s;
}

// Bucket the src indices by dst into CSR order.
__global__ __launch_bounds__(256) void fill_k(const int* __restrict__ ei,
                                              const int* __restrict__ flag,
                                              int* __restrict__ cursor,
                                              int* __restrict__ srcs) {
  int e = blockIdx.x * 256 + threadIdx.x;
  int src, dst;
  if (*flag) {
    src = ei[2 * (size_t)e];
    dst = ei[2 * (NE + (size_t)e)];
  } else {
    src = ei[e];
    dst = ei[NE + e];
  }
  int pos = atomicAdd(cursor + dst, 1);
  srcs[pos] = src;
}

// One wave per node: sum bf16 rows of its in-edges in fp32 regs (2 ch/lane),
// write the aggregated row once as bf16. Zero-degree nodes write zeros.
__global__ __launch_bounds__(256) void agg_k(const int* __restrict__ srcs,
                                             const int* __restrict__ offs,
                                             const unsigned short* __restrict__ hb,
                                             unsigned short* __restrict__ Sb) {
  const int w = (int)((blockIdx.x * 256u + threadIdx.x) >> 6);  // node id
  const int l = threadIdx.x & 63;
  const int beg = offs[w], end = offs[w + 1];
  float ax = 0.f, ay = 0.f;
  int e = beg;
  for (; e + 4 <= end; e += 4) {
    int s0 = srcs[e], s1 = srcs[e + 1], s2 = srcs[e + 2], s3 = srcs[e + 3];
    unsigned v0 = *(const unsigned*)(hb + (size_t)s0 * D + 2 * l);
    unsigned v1 = *(const unsigned*)(hb + (size_t)s1 * D + 2 * l);
    unsigned v2 = *(const unsigned*)(hb + (size_t)s2 * D + 2 * l);
    unsigned v3 = *(const unsigned*)(hb + (size_t)s3 * D + 2 * l);
    ax += b2f(v0 & 0xffff) + b2f(v1 & 0xffff) + b2f(v2 & 0xffff) + b2f(v3 & 0xffff);
    ay += b2f(v0 >> 16) + b2f(v1 >> 16) + b2f(v2 >> 16) + b2f(v3 >> 16);
  }
  for (; e < end; ++e) {
    unsigned v = *(const unsigned*)(hb + (size_t)srcs[e] * D + 2 * l);
    ax += b2f(v & 0xffff);
    ay += b2f(v >> 16);
  }
  unsigned o = (unsigned)f2b(ax) | ((unsigned)f2b(ay) << 16);
  *(unsigned*)(Sb + (size_t)w * D + 2 * l) = o;
}

// out = relu([h | agg] @ [W1 | Wc]^T + b), bf16 MFMA 16x16x32, K=256, N=128.
__global__ __launch_bounds__(256) void gemm_k(const unsigned short* __restrict__ hb,
                                              const unsigned short* __restrict__ Sb,
                                              const unsigned short* __restrict__ W1b,
                                              const unsigned short* __restrict__ Wcb,
                                              const float* __restrict__ bias,
                                              float* __restrict__ out) {
  const int wave = threadIdx.x >> 6;
  const int lane = threadIdx.x & 63;
  const int r = lane & 15;   // A-row / B-col / C-col within 16
  const int g = lane >> 4;   // k-group; C-row group
  const int row0 = blockIdx.x * 64 + wave * 16;
  const int row = min(row0 + r, NN - 1);  // clamp; stores are guarded

  f32x4 acc[8];
#pragma unroll
  for (int t = 0; t < 8; ++t) acc[t] = (f32x4){0.f, 0.f, 0.f, 0.f};

#pragma unroll
  for (int c = 0; c < 8; ++c) {
    const int k0 = (c & 3) * 32 + g * 8;
    const unsigned short* A = (c < 4) ? hb : Sb;
    short8 a = *(const short8*)(A + (size_t)row * D + k0);
    const unsigned short* W = (c < 4) ? W1b : Wcb;
#pragma unroll
    for (int t = 0; t < 8; ++t) {
      short8 b = *(const short8*)(W + (size_t)(t * 16 + r) * D + k0);
      acc[t] = __builtin_amdgcn_mfma_f32_16x16x32_bf16(a, b, acc[t], 0, 0, 0);
    }
  }

#pragma unroll
  for (int t = 0; t < 8; ++t) {
    const int col = t * 16 + r;
    const float bv = bias[col];
#pragma unroll
    for (int j = 0; j < 4; ++j) {
      const int orow = row0 + g * 4 + j;
      if (orow < NN) {
        float v = acc[t][j] + bv;
        out[(size_t)orow * D + col] = v > 0.f ? v : 0.f;
      }
    }
  }
}

extern "C" void kernel_launch(void* const* d_in, const int* in_sizes, int n_in,
                              void* d_out, int out_size, void* d_ws, size_t ws_size,
                              hipStream_t stream) {
  const float* h  = (const float*)d_in[0];
  const int*   ei = (const int*)d_in[1];
  const float* Wm = (const float*)d_in[2];
  const float* Wu = (const float*)d_in[3];
  const float* bu = (const float*)d_in[4];
  float* out = (float*)d_out;

  char* ws = (char*)d_ws;
  unsigned short* Sb   = (unsigned short*)(ws);               // 12,800,000 B
  unsigned short* hb   = (unsigned short*)(ws + 12800000);    // 12,800,000 B
  int*            srcs = (int*)(ws + 25600000);               //  6,400,000 B
  int*            offs = (int*)(ws + 32000000);               //    200,016 B (NN+1)
  int*            curs = (int*)(ws + 32200016);               //    200,000 B
  int*            cnt  = (int*)(ws + 32400016);               //    200,000 B
  unsigned short* W1b  = (unsigned short*)(ws + 32600016);    //     32,768 B
  unsigned short* Wcb  = (unsigned short*)(ws + 32632784);    //     32,768 B
  int*            flg  = (int*)(ws + 32665552);               //          4 B

  detect_k<<<1, 256, 0, stream>>>(ei, flg);
  prep_k<<<(NN * D / 4) / 256, 256, 0, stream>>>(h, hb, cnt);     // 6250 blocks
  wprep_k<<<64, 256, 0, stream>>>(Wm, Wu, W1b, Wcb);
  hist_k<<<NE / 256, 256, 0, stream>>>(ei, flg, cnt);             // 6250 blocks
  scan_k<<<1, 1024, 0, stream>>>(cnt, offs, curs);
  fill_k<<<NE / 256, 256, 0, stream>>>(ei, flg, curs, srcs);      // 6250 blocks
  agg_k<<<(NN * 64) / 256, 256, 0, stream>>>(srcs, offs, hb, Sb); // 12500 blocks
  gemm_k<<<(NN + 63) / 64, 256, 0, stream>>>(hb, Sb, W1b, Wcb, bu, out); // 782 blocks
}